// Round 1
// baseline (429.813 us; speedup 1.0000x reference)
//
#include <hip/hip_runtime.h>

// WindowAttention: B=8, C=128, H=W=256, ws=8, heads=4, d=32, n=64 tokens/window
// One block = one window (8192 blocks, 256 thr = 4 waves). Wave h owns head h.
// All GEMMs via v_mfma_f32_16x16x32_bf16, f32 accumulation; softmax/bias/output f32.

#define CCH   128
#define HH    256
#define WWID  256
#define SCALE 0.17677669529663687f

typedef float  f32x4  __attribute__((ext_vector_type(4)));
typedef __bf16 bf16x8 __attribute__((ext_vector_type(8)));
typedef short  s16x4  __attribute__((ext_vector_type(4)));
typedef unsigned short ushort_t;

// ---- LDS byte layout (64 KiB total, phase-overlaid) ----
// [0      ,16384): Q  : 4 heads x [64 tok][32 d] bf16   (phase B->C) / Ystage f32 lower half (D->E)
// [16384  ,32768): K  : 4 heads x [64 tok][32 d] bf16   (phase B->C) / Ystage f32 upper half (D->E)
// [32768  ,49152): V  : 4 heads x [32 d][64 tok] bf16   (phase B->C)
// [49152  ,65536): Xt [64 tok][128 c] bf16 (A->B) / P: 4 heads x [32][64] bf16 (C) / Ot [64][128] bf16 (C->D)
#define Q_OFF  0
#define K_OFF  16384
#define V_OFF  32768
#define XT_OFF 49152
#define Y_OFF  0

__device__ __forceinline__ ushort_t f2bf(float x) {
  unsigned u = __float_as_uint(x);
  u += 0x7fffu + ((u >> 16) & 1u);        // round-to-nearest-even
  return (ushort_t)(u >> 16);
}

__global__ void prep_weights(const float* __restrict__ wqkv,
                             const float* __restrict__ wproj,
                             ushort_t* __restrict__ wbf) {
  int i = blockIdx.x * 256 + threadIdx.x;          // 65536 total
  float v = (i < 49152) ? wqkv[i] : wproj[i - 49152];
  wbf[i] = f2bf(v);
}

__global__ __launch_bounds__(256, 2)
void winattn_main(const float* __restrict__ x,
                  const ushort_t* __restrict__ wqkv,   // [384][128] bf16
                  const ushort_t* __restrict__ wproj,  // [128][128] bf16
                  const float* __restrict__ bproj,
                  float* __restrict__ out) {
  __shared__ __align__(16) char smem[65536];

  const int tid  = threadIdx.x;
  const int lane = tid & 63;
  const int wv   = tid >> 6;       // wave id == head id
  const int l15  = lane & 15;
  const int l4   = lane >> 4;

  const int win = blockIdx.x;
  const int b   = win >> 10;
  const int wy  = (win >> 5) & 31;
  const int wx  = win & 31;
  const int gy0 = wy * 8, gx0 = wx * 8;

  // ---------------- Phase A: load window -> Xt[tok][c] bf16 (swizzled) ----------------
  #pragma unroll
  for (int it = 0; it < 4; ++it) {
    int idx   = tid + it * 256;        // 1024 tasks: (cpair 64) x (ty 8) x (tx4 2)
    int cpair = idx >> 4;
    int r     = idx & 15;
    int ty    = r >> 1, tx4 = r & 1;
    const float* px = x + (((size_t)(b * CCH + 2 * cpair) * HH + gy0 + ty) * WWID + gx0 + tx4 * 4);
    float4 v0 = *(const float4*)px;
    float4 v1 = *(const float4*)(px + (size_t)HH * WWID);
    float a0[4] = {v0.x, v0.y, v0.z, v0.w};
    float a1[4] = {v1.x, v1.y, v1.z, v1.w};
    #pragma unroll
    for (int i = 0; i < 4; ++i) {
      int tok = ty * 8 + tx4 * 4 + i;
      unsigned wword = (unsigned)f2bf(a0[i]) | ((unsigned)f2bf(a1[i]) << 16);
      int byte = XT_OFF + tok * 256 + cpair * 4;
      byte ^= (tok & 7) << 4;
      *(unsigned*)(smem + byte) = wword;
    }
  }
  __syncthreads();

  // ---------------- Phase B: QKV for head wv ----------------
  {
    bf16x8 af[4][4];   // A-fragments of Xt: [mtile][ktile]
    #pragma unroll
    for (int mt = 0; mt < 4; ++mt)
      #pragma unroll
      for (int kt = 0; kt < 4; ++kt) {
        int tok  = mt * 16 + l15;
        int byte = XT_OFF + tok * 256 + (kt * 32 + l4 * 8) * 2;
        byte ^= (tok & 7) << 4;
        af[mt][kt] = *(const bf16x8*)(smem + byte);
      }
    #pragma unroll
    for (int p = 0; p < 3; ++p) {        // 0=Q 1=K 2=V
      #pragma unroll
      for (int nt2 = 0; nt2 < 2; ++nt2) {
        int orow0 = p * 128 + wv * 32 + nt2 * 16;
        f32x4 acc[4] = {};
        #pragma unroll
        for (int kt = 0; kt < 4; ++kt) {
          bf16x8 bf = *(const bf16x8*)(wqkv + (size_t)(orow0 + l15) * 128 + kt * 32 + l4 * 8);
          #pragma unroll
          for (int mt = 0; mt < 4; ++mt)
            acc[mt] = __builtin_amdgcn_mfma_f32_16x16x32_bf16(af[mt][kt], bf, acc[mt], 0, 0, 0);
        }
        int dloc = nt2 * 16 + l15;   // 0..31 within head
        if (p < 2) {                 // Q,K token-major [64][32]
          int base = (p == 0 ? Q_OFF : K_OFF) + wv * 4096;
          #pragma unroll
          for (int mt = 0; mt < 4; ++mt)
            #pragma unroll
            for (int r = 0; r < 4; ++r) {
              int tok  = mt * 16 + l4 * 4 + r;
              int byte = base + tok * 64 + dloc * 2;
              byte ^= (tok & 3) << 4;
              *(ushort_t*)(smem + byte) = f2bf(acc[mt][r]);
            }
        } else {                     // V transposed [32 d][64 tok], packed 4-tok writes
          #pragma unroll
          for (int mt = 0; mt < 4; ++mt) {
            int tok0 = mt * 16 + l4 * 4;
            s16x4 wv4;
            #pragma unroll
            for (int r = 0; r < 4; ++r) wv4[r] = (short)f2bf(acc[mt][r]);
            int byte = V_OFF + wv * 4096 + dloc * 128 + tok0 * 2;
            byte ^= (dloc & 7) << 4;
            *(s16x4*)(smem + byte) = wv4;
          }
        }
      }
    }
  }
  __syncthreads();

  // ---------------- Phase C: attention for head wv (two 32-row halves) ----------------
  f32x4 oacc[2][2][2] = {};   // [half][row-tile][d-tile]
  {
    const int qb = Q_OFF + wv * 4096, kb = K_OFF + wv * 4096;
    const int vb = V_OFF + wv * 4096, pb = XT_OFF + wv * 4096;
    bf16x8 bk[4];              // K B-fragments (all 4 key tiles)
    #pragma unroll
    for (int mtS = 0; mtS < 4; ++mtS) {
      int m    = mtS * 16 + l15;
      int byte = kb + m * 64 + (l4 * 8) * 2;
      byte ^= (m & 3) << 4;
      bk[mtS] = *(const bf16x8*)(smem + byte);
    }
    bf16x8 bv[2][2];           // V B-fragments [d-tile][k-tile]
    #pragma unroll
    for (int vt = 0; vt < 2; ++vt)
      #pragma unroll
      for (int kt = 0; kt < 2; ++kt) {
        int d    = vt * 16 + l15;
        int byte = vb + d * 128 + (kt * 32 + l4 * 8) * 2;
        byte ^= (d & 7) << 4;
        bv[vt][kt] = *(const bf16x8*)(smem + byte);
      }
    #pragma unroll
    for (int hf = 0; hf < 2; ++hf) {
      // S = Q K^T (rows hf*32..hf*32+32)
      f32x4 s[2][4];
      #pragma unroll
      for (int qt = 0; qt < 2; ++qt) {
        int tok  = hf * 32 + qt * 16 + l15;
        int byte = qb + tok * 64 + (l4 * 8) * 2;
        byte ^= (tok & 3) << 4;
        bf16x8 aq = *(const bf16x8*)(smem + byte);
        #pragma unroll
        for (int mtS = 0; mtS < 4; ++mtS) {
          f32x4 z = {0.f, 0.f, 0.f, 0.f};
          s[qt][mtS] = __builtin_amdgcn_mfma_f32_16x16x32_bf16(aq, bk[mtS], z, 0, 0, 0);
        }
      }
      // row softmax + write P bf16 (P_h overlays dead Xt region)
      #pragma unroll
      for (int qt = 0; qt < 2; ++qt)
        #pragma unroll
        for (int r = 0; r < 4; ++r) {
          float v0 = s[qt][0][r] * SCALE, v1 = s[qt][1][r] * SCALE;
          float v2 = s[qt][2][r] * SCALE, v3 = s[qt][3][r] * SCALE;
          float mx = fmaxf(fmaxf(v0, v1), fmaxf(v2, v3));
          mx = fmaxf(mx, __shfl_xor(mx, 1));
          mx = fmaxf(mx, __shfl_xor(mx, 2));
          mx = fmaxf(mx, __shfl_xor(mx, 4));
          mx = fmaxf(mx, __shfl_xor(mx, 8));
          float e0 = __expf(v0 - mx), e1 = __expf(v1 - mx);
          float e2 = __expf(v2 - mx), e3 = __expf(v3 - mx);
          float sm = e0 + e1 + e2 + e3;
          sm += __shfl_xor(sm, 1);
          sm += __shfl_xor(sm, 2);
          sm += __shfl_xor(sm, 4);
          sm += __shfl_xor(sm, 8);
          float inv = 1.0f / sm;
          int nl = qt * 16 + l4 * 4 + r;          // local row 0..31
          int rowb = pb + nl * 128;
          int sw   = (nl & 7) << 4;
          *(ushort_t*)(smem + (((rowb + (0 * 16 + l15) * 2)) ^ sw)) = f2bf(e0 * inv);
          *(ushort_t*)(smem + (((rowb + (1 * 16 + l15) * 2)) ^ sw)) = f2bf(e1 * inv);
          *(ushort_t*)(smem + (((rowb + (2 * 16 + l15) * 2)) ^ sw)) = f2bf(e2 * inv);
          *(ushort_t*)(smem + (((rowb + (3 * 16 + l15) * 2)) ^ sw)) = f2bf(e3 * inv);
        }
      // O += P V  (accumulate in registers)
      #pragma unroll
      for (int kt = 0; kt < 2; ++kt)
        #pragma unroll
        for (int rt = 0; rt < 2; ++rt) {
          int nl   = rt * 16 + l15;
          int byte = pb + nl * 128 + (kt * 32 + l4 * 8) * 2;
          byte ^= (nl & 7) << 4;
          bf16x8 ap = *(const bf16x8*)(smem + byte);
          #pragma unroll
          for (int vt = 0; vt < 2; ++vt)
            oacc[hf][rt][vt] =
                __builtin_amdgcn_mfma_f32_16x16x32_bf16(ap, bv[vt][kt], oacc[hf][rt][vt], 0, 0, 0);
        }
    }
  }
  __syncthreads();   // everyone done reading P -> safe to overlay Ot onto that region

  // write Ot[64 tok][128 c] bf16 into XT region
  #pragma unroll
  for (int hf = 0; hf < 2; ++hf)
    #pragma unroll
    for (int rt = 0; rt < 2; ++rt)
      #pragma unroll
      for (int vt = 0; vt < 2; ++vt)
        #pragma unroll
        for (int r = 0; r < 4; ++r) {
          int tok  = hf * 32 + rt * 16 + l4 * 4 + r;
          int c    = wv * 32 + vt * 16 + l15;
          int byte = XT_OFF + tok * 256 + c * 2;
          byte ^= (tok & 7) << 4;
          *(ushort_t*)(smem + byte) = f2bf(oacc[hf][rt][vt][r]);
        }
  __syncthreads();

  // ---------------- Phase D: proj GEMM -> Ystage f32 (overlays Q/K region) ----------------
  {
    bf16x8 ao[4][4];
    #pragma unroll
    for (int mt = 0; mt < 4; ++mt)
      #pragma unroll
      for (int kt = 0; kt < 4; ++kt) {
        int tok  = mt * 16 + l15;
        int byte = XT_OFF + tok * 256 + (kt * 32 + l4 * 8) * 2;
        byte ^= (tok & 7) << 4;
        ao[mt][kt] = *(const bf16x8*)(smem + byte);
      }
    #pragma unroll
    for (int i = 0; i < 2; ++i) {
      int orow0 = (wv * 2 + i) * 16;
      f32x4 acc[4] = {};
      #pragma unroll
      for (int kt = 0; kt < 4; ++kt) {
        bf16x8 bf = *(const bf16x8*)(wproj + (size_t)(orow0 + l15) * 128 + kt * 32 + l4 * 8);
        #pragma unroll
        for (int mt = 0; mt < 4; ++mt)
          acc[mt] = __builtin_amdgcn_mfma_f32_16x16x32_bf16(ao[mt][kt], bf, acc[mt], 0, 0, 0);
      }
      #pragma unroll
      for (int mt = 0; mt < 4; ++mt)
        #pragma unroll
        for (int r = 0; r < 4; ++r) {
          int tok  = mt * 16 + l4 * 4 + r;
          int o    = orow0 + l15;
          int byte = Y_OFF + tok * 512 + o * 4;
          byte ^= (tok & 7) << 4;
          *(float*)(smem + byte) = acc[mt][r];
        }
    }
  }
  __syncthreads();

  // ---------------- Phase E: bias + coalesced writeout ----------------
  #pragma unroll
  for (int it = 0; it < 4; ++it) {
    int idx = tid + it * 256;     // 1024 tasks: (o 128) x (ty 8)
    int o   = idx & 127;
    int ty  = idx >> 7;
    float bias = bproj[o];
    float vals[8];
    #pragma unroll
    for (int tx = 0; tx < 8; ++tx) {
      int tok  = ty * 8 + tx;
      int byte = Y_OFF + tok * 512 + o * 4;
      byte ^= (tok & 7) << 4;
      vals[tx] = *(const float*)(smem + byte) + bias;
    }
    float4 f0 = {vals[0], vals[1], vals[2], vals[3]};
    float4 f1 = {vals[4], vals[5], vals[6], vals[7]};
    float* po = out + (((size_t)(b * CCH + o) * HH + gy0 + ty) * WWID + gx0);
    *(float4*)po       = f0;
    *(float4*)(po + 4) = f1;
  }
}

extern "C" void kernel_launch(void* const* d_in, const int* in_sizes, int n_in,
                              void* d_out, int out_size, void* d_ws, size_t ws_size,
                              hipStream_t stream) {
  const float* x     = (const float*)d_in[0];
  const float* wqkv  = (const float*)d_in[1];
  const float* wproj = (const float*)d_in[2];
  const float* bproj = (const float*)d_in[3];
  float* out = (float*)d_out;

  ushort_t* wbf = (ushort_t*)d_ws;   // 65536 bf16 = 128 KiB scratch
  prep_weights<<<256, 256, 0, stream>>>(wqkv, wproj, wbf);
  winattn_main<<<8192, 256, 0, stream>>>(x, wbf, wbf + 49152, bproj, out);
}